// Round 1
// baseline (205.437 us; speedup 1.0000x reference)
//
#include <hip/hip_runtime.h>

typedef unsigned short u16;
typedef __attribute__((ext_vector_type(4))) float f4;
typedef __attribute__((ext_vector_type(4))) unsigned short us4;
typedef __attribute__((ext_vector_type(8))) short s8v;
typedef __attribute__((ext_vector_type(4))) float f32x4;

#define DEVI __device__ __forceinline__

DEVI u16 f2bf(float f) {
  unsigned u = __float_as_uint(f);
  u = (u + 0x7FFFu + ((u >> 16) & 1u)) >> 16;
  return (u16)u;
}
DEVI float siluf(float x) { return x / (1.f + __expf(-x)); }

// ---------------- converts ----------------
__global__ void k_cvt4(const float* __restrict__ in, u16* __restrict__ out, int nq) {
  int i = blockIdx.x * 256 + threadIdx.x;
  if (i >= nq) return;
  f4 v = ((const f4*)in)[i];
  us4 o;
#pragma unroll
  for (int j = 0; j < 4; ++j) o[j] = f2bf(v[j]);
  ((us4*)out)[i] = o;
}

// W_x (96x1024) -> bf16 padded to 128 rows (zeros)
__global__ void k_cvt_wx(const float* __restrict__ in, u16* __restrict__ out) {
  int i = blockIdx.x * 256 + threadIdx.x;  // quads over 128*1024/4
  int row = i >> 8;
  us4 o;
  if (row < 96) {
    f4 v = ((const f4*)in)[i];
#pragma unroll
    for (int j = 0; j < 4; ++j) o[j] = f2bf(v[j]);
  } else {
    o[0] = 0; o[1] = 0; o[2] = 0; o[3] = 0;
  }
  ((us4*)out)[i] = o;
}

__global__ void k_zero(float* __restrict__ p, int n) {
  int i = blockIdx.x * 256 + threadIdx.x;
  if (i < n) p[i] = 0.f;
}

// ---------------- bf16 NT GEMM (m97 structure: 128x128 tile, BK=32, 4 waves) ----
// C[M][N] (fp32) = A[M][K]bf16 * B[N][K]bf16^T
// EPI: 0 = plain store, 1 = store * silu(zsrc[row*zld+zoff+col]), 2 = atomicAdd
template <int EPI>
__global__ void k_gemm_bt(const u16* __restrict__ A, int lda,
                          const u16* __restrict__ B, int ldb,
                          float* __restrict__ C, int ldc, int nvalid,
                          int K, int kchunk,
                          const float* __restrict__ zsrc, int zld, int zoff) {
  __shared__ __align__(16) u16 As[128 * 32];
  __shared__ __align__(16) u16 Bs[128 * 32];
  const int tid = threadIdx.x;
  const int wave = tid >> 6, lane = tid & 63;
  const int mBase = blockIdx.y << 7;
  const int nBase = blockIdx.x << 7;
  const int kbeg = blockIdx.z * kchunk;
  int kend = kbeg + kchunk; if (kend > K) kend = K;

  const int wr = wave >> 1, wc = wave & 1;
  const int row0 = tid >> 2, kg = tid & 3;

  const u16* Ag0 = A + (size_t)(mBase + row0) * lda + kg * 8;
  const u16* Ag1 = A + (size_t)(mBase + 64 + row0) * lda + kg * 8;
  const u16* Bg0 = B + (size_t)(nBase + row0) * ldb + kg * 8;
  const u16* Bg1 = B + (size_t)(nBase + 64 + row0) * ldb + kg * 8;
  char* ldsA = (char*)As + wave * 1024;
  char* ldsB = (char*)Bs + wave * 1024;

  const int fr = lane & 15, fk = (lane >> 4) << 3;
  const int aoff = ((wr << 6) + fr) * 32 + fk;
  const int boff = ((wc << 6) + fr) * 32 + fk;

  f32x4 acc[4][4];
#pragma unroll
  for (int m = 0; m < 4; ++m)
#pragma unroll
    for (int n = 0; n < 4; ++n) acc[m][n] = {0.f, 0.f, 0.f, 0.f};

  for (int k0 = kbeg; k0 < kend; k0 += 32) {
    __syncthreads();
    __builtin_amdgcn_global_load_lds((const __attribute__((address_space(1))) void*)(Ag0 + k0),
                                     (__attribute__((address_space(3))) void*)(ldsA), 16, 0, 0);
    __builtin_amdgcn_global_load_lds((const __attribute__((address_space(1))) void*)(Ag1 + k0),
                                     (__attribute__((address_space(3))) void*)(ldsA + 4096), 16, 0, 0);
    __builtin_amdgcn_global_load_lds((const __attribute__((address_space(1))) void*)(Bg0 + k0),
                                     (__attribute__((address_space(3))) void*)(ldsB), 16, 0, 0);
    __builtin_amdgcn_global_load_lds((const __attribute__((address_space(1))) void*)(Bg1 + k0),
                                     (__attribute__((address_space(3))) void*)(ldsB + 4096), 16, 0, 0);
    __syncthreads();
    s8v av[4], bv[4];
#pragma unroll
    for (int m = 0; m < 4; ++m) av[m] = *(const s8v*)(As + aoff + (m << 9));
#pragma unroll
    for (int n = 0; n < 4; ++n) bv[n] = *(const s8v*)(Bs + boff + (n << 9));
#pragma unroll
    for (int m = 0; m < 4; ++m)
#pragma unroll
      for (int n = 0; n < 4; ++n)
        acc[m][n] = __builtin_amdgcn_mfma_f32_16x16x32_bf16(av[m], bv[n], acc[m][n], 0, 0, 0);
  }

  // C/D layout (m89-verified): col = lane&15, row = (lane>>4)*4 + j
  const int crow0 = mBase + (wr << 6) + ((lane >> 4) << 2);
  const int ccol0 = nBase + (wc << 6) + (lane & 15);
#pragma unroll
  for (int m = 0; m < 4; ++m) {
#pragma unroll
    for (int n = 0; n < 4; ++n) {
      const int cc = ccol0 + (n << 4);
      if (cc < nvalid) {
#pragma unroll
        for (int j = 0; j < 4; ++j) {
          const int rr = crow0 + (m << 4) + j;
          float v = acc[m][n][j];
          if (EPI == 1) v *= siluf(zsrc[(size_t)rr * zld + zoff + cc]);
          if (EPI == 2) atomicAdd(&C[(size_t)rr * ldc + cc], v);
          else C[(size_t)rr * ldc + cc] = v;
        }
      }
    }
  }
}

// ---------------- conv(width3, same-pad per batch) + silu ----------------
__global__ void k_conv_silu(const float* __restrict__ xz, const float* __restrict__ conv_w,
                            float* __restrict__ xs_f, u16* __restrict__ xsb) {
  const int bt = blockIdx.x;       // 0..4095
  const int d = threadIdx.x << 2;  // 0..1020
  const int t = bt & 2047;
  const float* rowm = xz + (size_t)bt * 2048 + d;
  f4 mid = *(const f4*)rowm;
  f4 lft = {0.f, 0.f, 0.f, 0.f}, rgt = {0.f, 0.f, 0.f, 0.f};
  if (t > 0)    lft = *(const f4*)(rowm - 2048);
  if (t < 2047) rgt = *(const f4*)(rowm + 2048);
  const f4* cw = (const f4*)(conv_w + d * 3);
  f4 c0 = cw[0], c1 = cw[1], c2 = cw[2];
  float w[12] = {c0[0], c0[1], c0[2], c0[3], c1[0], c1[1], c1[2], c1[3],
                 c2[0], c2[1], c2[2], c2[3]};
  f4 xs; us4 xb;
#pragma unroll
  for (int j = 0; j < 4; ++j) {
    float xc = lft[j] * w[j * 3] + mid[j] * w[j * 3 + 1] + rgt[j] * w[j * 3 + 2];
    float s = siluf(xc);
    xs[j] = s; xb[j] = f2bf(s);
  }
  *(f4*)(xs_f + (size_t)bt * 1024 + d) = xs;
  *(us4*)(xsb + (size_t)bt * 1024 + d) = xb;
}

// ---------------- dt=softplus(dtg+b)+1e-5 (in-place), dtx=dt*xs, C-proj ---
__global__ void k_epi1(float* __restrict__ dtg, const float* __restrict__ b_dt,
                       const float* __restrict__ xs_f, const float* __restrict__ xdbl,
                       const float* __restrict__ W_C,
                       float* __restrict__ DTX, float* __restrict__ CPROJ) {
  const int bt = blockIdx.x >> 2;
  const int d = ((blockIdx.x & 3) << 8) + threadIdx.x;
  const size_t i = (size_t)bt * 1024 + d;
  float pre = dtg[i] + b_dt[d];
  float dt = (pre > 20.f ? pre : log1pf(__expf(pre))) + 1e-5f;
  const f4* cp4 = (const f4*)(xdbl + (size_t)bt * 96 + 80);
  const f4* wc4 = (const f4*)(W_C + d * 16);
  float cp = 0.f;
#pragma unroll
  for (int q = 0; q < 4; ++q) {
    f4 a = cp4[q], b = wc4[q];
    cp += a[0] * b[0] + a[1] * b[1] + a[2] * b[2] + a[3] * b[3];
  }
  dtg[i] = dt;
  DTX[i] = dt * xs_f[i];
  CPROJ[i] = cp;
}

// ---------------- chunked scan: L=64, NC=32 ----------------
// pass A: per (b,d,chunk): P[n]=prod A, S[n]=chunk-local end state
__global__ void k_scanA(const float* __restrict__ DT, const float* __restrict__ DTX,
                        const float* __restrict__ xdbl, const float* __restrict__ A_log,
                        float* __restrict__ Pc, float* __restrict__ Sc) {
  const int d = (blockIdx.x << 8) + threadIdx.x;
  const int c = blockIdx.y;
  const int b = blockIdx.z;
  float a[16];
  {
    const f4* al = (const f4*)(A_log + d * 16);
#pragma unroll
    for (int q = 0; q < 4; ++q) {
      f4 v = al[q];
#pragma unroll
      for (int j = 0; j < 4; ++j) a[q * 4 + j] = -__expf(v[j]);
    }
  }
  float P[16], S[16];
#pragma unroll
  for (int n = 0; n < 16; ++n) { P[n] = 1.f; S[n] = 0.f; }
  const int btBase = (b << 11) + (c << 6);
  for (int tau = 0; tau < 64; ++tau) {
    const size_t bt = btBase + tau;
    const float dt = DT[(bt << 10) + d];
    const float dx = DTX[(bt << 10) + d];
    const f4* bp4 = (const f4*)(xdbl + bt * 96 + 64);
    f4 bq[4];
#pragma unroll
    for (int q = 0; q < 4; ++q) bq[q] = bp4[q];
#pragma unroll
    for (int n = 0; n < 16; ++n) {
      const float Av = __expf(a[n] * dt);
      P[n] *= Av;
      S[n] = fmaf(Av, S[n], bq[n >> 2][n & 3] * dx);
    }
  }
  const size_t base = ((((size_t)b << 10) + d) * 32 + c) << 4;
#pragma unroll
  for (int q = 0; q < 4; ++q) {
    f4 pv, sv;
#pragma unroll
    for (int j = 0; j < 4; ++j) { pv[j] = P[q * 4 + j]; sv[j] = S[q * 4 + j]; }
    *(f4*)(Pc + base + q * 4) = pv;
    *(f4*)(Sc + base + q * 4) = sv;
  }
}

// pass B: per (b,d,n): sequential combine of 32 chunk summaries -> chunk init states
__global__ void k_scanB(const float* __restrict__ Pc, const float* __restrict__ Sc,
                        float* __restrict__ SI) {
  const int i = (blockIdx.x << 8) + threadIdx.x;  // 32768
  const int n = i & 15;
  const int dd = (i >> 4) & 1023;
  const int b = i >> 14;
  const size_t base = ((((size_t)b << 10) + dd) << 9) + n;  // (b*1024+dd)*512 + n
  float s = 0.f;
  for (int c = 0; c < 32; ++c) {
    const size_t idx = base + ((size_t)c << 4);
    SI[idx] = s;
    s = fmaf(Pc[idx], s, Sc[idx]);
  }
}

// pass C: replay chunk with known init state; emit y (bf16) directly
__global__ void k_scanC(const float* __restrict__ DT, const float* __restrict__ DTX,
                        const float* __restrict__ xdbl, const float* __restrict__ A_log,
                        const float* __restrict__ SI, const float* __restrict__ CPROJ,
                        const float* __restrict__ xs_f, const float* __restrict__ D_param,
                        u16* __restrict__ yb) {
  const int d = (blockIdx.x << 8) + threadIdx.x;
  const int c = blockIdx.y;
  const int b = blockIdx.z;
  float a[16];
  {
    const f4* al = (const f4*)(A_log + d * 16);
#pragma unroll
    for (int q = 0; q < 4; ++q) {
      f4 v = al[q];
#pragma unroll
      for (int j = 0; j < 4; ++j) a[q * 4 + j] = -__expf(v[j]);
    }
  }
  float s[16];
  const size_t base = ((((size_t)b << 10) + d) * 32 + c) << 4;
#pragma unroll
  for (int q = 0; q < 4; ++q) {
    f4 v = *(const f4*)(SI + base + q * 4);
#pragma unroll
    for (int j = 0; j < 4; ++j) s[q * 4 + j] = v[j];
  }
  const float Dp = D_param[d];
  const int btBase = (b << 11) + (c << 6);
  for (int tau = 0; tau < 64; ++tau) {
    const size_t bt = btBase + tau;
    const float dt = DT[(bt << 10) + d];
    const float dx = DTX[(bt << 10) + d];
    const f4* bp4 = (const f4*)(xdbl + bt * 96 + 64);
    f4 bq[4];
#pragma unroll
    for (int q = 0; q < 4; ++q) bq[q] = bp4[q];
    float ssum = 0.f;
#pragma unroll
    for (int n = 0; n < 16; ++n) {
      const float Av = __expf(a[n] * dt);
      s[n] = fmaf(Av, s[n], bq[n >> 2][n & 3] * dx);
      ssum += s[n];
    }
    const float y = fmaf(CPROJ[(bt << 10) + d], ssum, Dp * xs_f[(bt << 10) + d]);
    yb[(bt << 10) + d] = f2bf(y);
  }
}

extern "C" void kernel_launch(void* const* d_in, const int* in_sizes, int n_in,
                              void* d_out, int out_size, void* d_ws, size_t ws_size,
                              hipStream_t stream) {
  const float* x     = (const float*)d_in[0];
  const float* W_in  = (const float*)d_in[1];
  const float* convw = (const float*)d_in[2];
  const float* W_x   = (const float*)d_in[3];
  const float* W_dt  = (const float*)d_in[4];
  const float* b_dt  = (const float*)d_in[5];
  const float* A_log = (const float*)d_in[6];
  const float* D_par = (const float*)d_in[7];
  const float* W_C   = (const float*)d_in[8];
  const float* W_out = (const float*)d_in[9];
  float* out = (float*)d_out;
  (void)in_sizes; (void)n_in; (void)out_size; (void)ws_size;

  char* w = (char*)d_ws;
  auto take = [&](size_t bytes) { char* p = w; w += (bytes + 255) & ~(size_t)255; return p; };
  u16* xb     = (u16*)take(8388608);    // x bf16 [4096][1024]
  u16* w1b    = (u16*)take(4194304);    // W_in bf16 [2048][1024]
  u16* wxb    = (u16*)take(262144);     // W_x bf16 padded [128][1024]
  u16* wob    = (u16*)take(2097152);    // W_out bf16 [1024][1024]
  u16* wdtb   = (u16*)take(131072);     // W_dt bf16 [1024][64]
  u16* xdblb  = (u16*)take(786432);     // x_dbl bf16 [4096][96]
  u16* yb     = (u16*)take(8388608);    // y bf16 [4096][1024]
  u16* xsb    = (u16*)take(8388608);    // xs bf16 [4096][1024]
  float* xz   = (float*)take(33554432); // [4096][2048]
  float* xs_f = (float*)take(16777216); // [4096][1024]
  float* xdbl = (float*)take(1572864);  // [4096][96]
  float* dtg  = (float*)take(16777216); // dt pre-act, then dt (in-place)
  float* DTX  = (float*)take(16777216); // dt*xs
  float* CPROJ= (float*)take(16777216); // Cp @ W_C^T
  float* Pc   = (float*)take(4194304);  // [b][d][c][n]
  float* Sc   = (float*)take(4194304);
  float* SI   = (float*)take(4194304);

  // converts + zero
  k_cvt4<<<4096, 256, 0, stream>>>(x, xb, 1048576);
  k_cvt4<<<2048, 256, 0, stream>>>(W_in, w1b, 524288);
  k_cvt4<<<1024, 256, 0, stream>>>(W_out, wob, 262144);
  k_cvt4<<<64, 256, 0, stream>>>(W_dt, wdtb, 16384);
  k_cvt_wx<<<128, 256, 0, stream>>>(W_x, wxb);
  k_zero<<<1536, 256, 0, stream>>>(xdbl, 393216);

  // GEMM1: xz = x @ W_in^T  (4096 x 2048 x 1024)
  dim3 g1(16, 32, 1);
  k_gemm_bt<0><<<g1, 256, 0, stream>>>(xb, 1024, w1b, 1024, xz, 2048, 2048, 1024, 1024,
                                       nullptr, 0, 0);
  // conv + silu
  k_conv_silu<<<4096, 256, 0, stream>>>(xz, convw, xs_f, xsb);
  // GEMM2: x_dbl = xs @ W_x^T (split-K=4, atomic)
  dim3 g2(1, 32, 4);
  k_gemm_bt<2><<<g2, 256, 0, stream>>>(xsb, 1024, wxb, 1024, xdbl, 96, 96, 1024, 256,
                                       nullptr, 0, 0);
  k_cvt4<<<384, 256, 0, stream>>>(xdbl, xdblb, 98304);
  // dt GEMM: dtg = dt_param @ W_dt^T (K=64)
  dim3 g4(8, 32, 1);
  k_gemm_bt<0><<<g4, 256, 0, stream>>>(xdblb, 96, wdtb, 64, dtg, 1024, 1024, 64, 64,
                                       nullptr, 0, 0);
  // softplus/dtx/C-proj
  k_epi1<<<16384, 256, 0, stream>>>(dtg, b_dt, xs_f, xdbl, W_C, DTX, CPROJ);
  // chunked scan
  dim3 gs(4, 32, 2);
  k_scanA<<<gs, 256, 0, stream>>>(dtg, DTX, xdbl, A_log, Pc, Sc);
  k_scanB<<<128, 256, 0, stream>>>(Pc, Sc, SI);
  k_scanC<<<gs, 256, 0, stream>>>(dtg, DTX, xdbl, A_log, SI, CPROJ, xs_f, D_par, yb);
  // GEMM3: out = (y @ W_out^T) * silu(z)
  dim3 g3(8, 32, 1);
  k_gemm_bt<1><<<g3, 256, 0, stream>>>(yb, 1024, wob, 1024, out, 1024, 1024, 1024, 1024,
                                       xz, 2048, 1024);
}

// Round 2
// 149.906 us; speedup vs baseline: 1.3704x; 1.3704x over previous
//
#include <hip/hip_runtime.h>

typedef unsigned short u16;
typedef __attribute__((ext_vector_type(4))) float f4;
typedef __attribute__((ext_vector_type(4))) unsigned short us4;
typedef __attribute__((ext_vector_type(8))) short s8v;
typedef __attribute__((ext_vector_type(4))) float f32x4;

#define DEVI __device__ __forceinline__

DEVI u16 f2bf(float f) {
  unsigned u = __float_as_uint(f);
  u = (u + 0x7FFFu + ((u >> 16) & 1u)) >> 16;
  return (u16)u;
}
DEVI float bf2f(u16 v) { return __uint_as_float(((unsigned)v) << 16); }
DEVI float siluf(float x) { return x / (1.f + __expf(-x)); }

// ---------------- fused converts (x, W_in, W_out, W_dt, W_x-padded) -------
__global__ void k_cvt_all(const float* __restrict__ x, const float* __restrict__ w1,
                          const float* __restrict__ wo, const float* __restrict__ wdt,
                          const float* __restrict__ wx,
                          u16* __restrict__ xb, u16* __restrict__ w1b,
                          u16* __restrict__ wob, u16* __restrict__ wdtb,
                          u16* __restrict__ wxb) {
  const int blk = blockIdx.x;
  const int tid = threadIdx.x;
  if (blk >= 7232) {  // W_x: 96x1024 -> 128x1024 zero-padded
    int i = (blk - 7232) * 256 + tid;
    int row = i >> 8;
    us4 o;
    if (row < 96) {
      f4 v = ((const f4*)wx)[i];
#pragma unroll
      for (int j = 0; j < 4; ++j) o[j] = f2bf(v[j]);
    } else {
      o[0] = 0; o[1] = 0; o[2] = 0; o[3] = 0;
    }
    ((us4*)wxb)[i] = o;
    return;
  }
  const float* src; u16* dst; int i;
  if (blk < 4096)      { src = x;   dst = xb;   i = blk * 256 + tid; }
  else if (blk < 6144) { src = w1;  dst = w1b;  i = (blk - 4096) * 256 + tid; }
  else if (blk < 7168) { src = wo;  dst = wob;  i = (blk - 6144) * 256 + tid; }
  else                 { src = wdt; dst = wdtb; i = (blk - 7168) * 256 + tid; }
  f4 v = ((const f4*)src)[i];
  us4 o;
#pragma unroll
  for (int j = 0; j < 4; ++j) o[j] = f2bf(v[j]);
  ((us4*)dst)[i] = o;
}

// ---------------- bf16 NT GEMM (m97 structure + XCD swizzle) ----------------
// C[M][N] fp32 = A[M][K]bf16 * B[N][K]bf16^T
// EPI: 0 = plain store (C += blockIdx.z*zstride for split-K parts),
//      1 = store * silu(zsrc[row*zld+zoff+col])
template <int EPI>
__global__ void k_gemm_bt(const u16* __restrict__ A, int lda,
                          const u16* __restrict__ B, int ldb,
                          float* __restrict__ C, int ldc, int nvalid,
                          int K, int kchunk, size_t zstride, int lognx,
                          const float* __restrict__ zsrc, int zld, int zoff) {
  __shared__ __align__(16) u16 As[128 * 32];
  __shared__ __align__(16) u16 Bs[128 * 32];
  const int tid = threadIdx.x;
  const int wave = tid >> 6, lane = tid & 63;

  // XCD-aware bijective swizzle (nwg % 8 == 0 for all call sites)
  const int nwg = gridDim.x * gridDim.y;
  int bid = blockIdx.y * gridDim.x + blockIdx.x;
  {
    const int cpx = nwg >> 3;
    bid = (bid & 7) * cpx + (bid >> 3);
  }
  const int mBase = (bid >> lognx) << 7;
  const int nBase = (bid & ((1 << lognx) - 1)) << 7;
  const int kbeg = blockIdx.z * kchunk;
  int kend = kbeg + kchunk; if (kend > K) kend = K;
  C += (size_t)blockIdx.z * zstride;

  const int wr = wave >> 1, wc = wave & 1;
  const int row0 = tid >> 2, kg = tid & 3;

  const u16* Ag0 = A + (size_t)(mBase + row0) * lda + kg * 8;
  const u16* Ag1 = A + (size_t)(mBase + 64 + row0) * lda + kg * 8;
  const u16* Bg0 = B + (size_t)(nBase + row0) * ldb + kg * 8;
  const u16* Bg1 = B + (size_t)(nBase + 64 + row0) * ldb + kg * 8;
  char* ldsA = (char*)As + wave * 1024;
  char* ldsB = (char*)Bs + wave * 1024;

  const int fr = lane & 15, fk = (lane >> 4) << 3;
  const int aoff = ((wr << 6) + fr) * 32 + fk;
  const int boff = ((wc << 6) + fr) * 32 + fk;

  f32x4 acc[4][4];
#pragma unroll
  for (int m = 0; m < 4; ++m)
#pragma unroll
    for (int n = 0; n < 4; ++n) acc[m][n] = {0.f, 0.f, 0.f, 0.f};

  for (int k0 = kbeg; k0 < kend; k0 += 32) {
    __syncthreads();
    __builtin_amdgcn_global_load_lds((const __attribute__((address_space(1))) void*)(Ag0 + k0),
                                     (__attribute__((address_space(3))) void*)(ldsA), 16, 0, 0);
    __builtin_amdgcn_global_load_lds((const __attribute__((address_space(1))) void*)(Ag1 + k0),
                                     (__attribute__((address_space(3))) void*)(ldsA + 4096), 16, 0, 0);
    __builtin_amdgcn_global_load_lds((const __attribute__((address_space(1))) void*)(Bg0 + k0),
                                     (__attribute__((address_space(3))) void*)(ldsB), 16, 0, 0);
    __builtin_amdgcn_global_load_lds((const __attribute__((address_space(1))) void*)(Bg1 + k0),
                                     (__attribute__((address_space(3))) void*)(ldsB + 4096), 16, 0, 0);
    __syncthreads();
    s8v av[4], bv[4];
#pragma unroll
    for (int m = 0; m < 4; ++m) av[m] = *(const s8v*)(As + aoff + (m << 9));
#pragma unroll
    for (int n = 0; n < 4; ++n) bv[n] = *(const s8v*)(Bs + boff + (n << 9));
#pragma unroll
    for (int m = 0; m < 4; ++m)
#pragma unroll
      for (int n = 0; n < 4; ++n)
        acc[m][n] = __builtin_amdgcn_mfma_f32_16x16x32_bf16(av[m], bv[n], acc[m][n], 0, 0, 0);
  }

  const int crow0 = mBase + (wr << 6) + ((lane >> 4) << 2);
  const int ccol0 = nBase + (wc << 6) + (lane & 15);
#pragma unroll
  for (int m = 0; m < 4; ++m) {
#pragma unroll
    for (int n = 0; n < 4; ++n) {
      const int cc = ccol0 + (n << 4);
      if (cc < nvalid) {
#pragma unroll
        for (int j = 0; j < 4; ++j) {
          const int rr = crow0 + (m << 4) + j;
          float v = acc[m][n][j];
          if (EPI == 1) v *= siluf(zsrc[(size_t)rr * zld + zoff + cc]);
          C[(size_t)rr * ldc + cc] = v;
        }
      }
    }
  }
}

// ---------------- split-K reduce (4 parts) + bf16 convert ----------------
__global__ void k_red4(const float* __restrict__ parts, float* __restrict__ xdbl,
                       u16* __restrict__ xdblb) {
  const int i = blockIdx.x * 256 + threadIdx.x;  // quads over 4096*96/4 = 98304
  f4 s = ((const f4*)parts)[i];
#pragma unroll
  for (int z = 1; z < 4; ++z) {
    f4 v = ((const f4*)(parts + (size_t)z * 393216))[i];
#pragma unroll
    for (int j = 0; j < 4; ++j) s[j] += v[j];
  }
  ((f4*)xdbl)[i] = s;
  us4 o;
#pragma unroll
  for (int j = 0; j < 4; ++j) o[j] = f2bf(s[j]);
  ((us4*)xdblb)[i] = o;
}

// ---------------- conv(width3) + silu, rolling window, 8 t per block -----
__global__ void k_conv2(const float* __restrict__ xz, const float* __restrict__ conv_w,
                        u16* __restrict__ xsb) {
  const int b = blockIdx.x >> 8;
  const int t0 = (blockIdx.x & 255) << 3;
  const int d = threadIdx.x << 2;
  const float* base = xz + (size_t)b * 2048 * 2048 + d;
  const f4* cw = (const f4*)(conv_w + d * 3);
  f4 c0 = cw[0], c1 = cw[1], c2 = cw[2];
  const float w[12] = {c0[0], c0[1], c0[2], c0[3], c1[0], c1[1], c1[2], c1[3],
                       c2[0], c2[1], c2[2], c2[3]};
  const f4 zero = {0.f, 0.f, 0.f, 0.f};
  f4 prev = (t0 == 0) ? zero : *(const f4*)(base + (size_t)(t0 - 1) * 2048);
  f4 cur = *(const f4*)(base + (size_t)t0 * 2048);
#pragma unroll
  for (int i = 0; i < 8; ++i) {
    const int t = t0 + i;
    f4 nxt = (t == 2047) ? zero : *(const f4*)(base + (size_t)(t + 1) * 2048);
    us4 xbv;
#pragma unroll
    for (int j = 0; j < 4; ++j) {
      float xc = prev[j] * w[j * 3] + cur[j] * w[j * 3 + 1] + nxt[j] * w[j * 3 + 2];
      xbv[j] = f2bf(siluf(xc));
    }
    *(us4*)(xsb + ((size_t)(b * 2048 + t) << 10) + d) = xbv;
    prev = cur; cur = nxt;
  }
}

// ---------------- chunked scan: L=32, NC=64, layout [b][c][d][n] ----------
__global__ void k_scanA(const float* __restrict__ dtg, const float* __restrict__ b_dt,
                        const u16* __restrict__ xsb, const float* __restrict__ xdbl,
                        const float* __restrict__ A_log,
                        float* __restrict__ Pc, float* __restrict__ Sc) {
  __shared__ float bxs[32][16];
  const int tid = threadIdx.x;
  const int d = (blockIdx.x << 8) + tid;
  const int c = blockIdx.y;
  const int b = blockIdx.z;
  const int btBase = (b << 11) + (c << 5);
  for (int i = tid; i < 512; i += 256) {
    bxs[i >> 4][i & 15] = xdbl[(size_t)(btBase + (i >> 4)) * 96 + 64 + (i & 15)];
  }
  float a[16];
  {
    const f4* al = (const f4*)(A_log + d * 16);
#pragma unroll
    for (int q = 0; q < 4; ++q) {
      f4 v = al[q];
#pragma unroll
      for (int j = 0; j < 4; ++j) a[q * 4 + j] = -__expf(v[j]);
    }
  }
  const float bd = b_dt[d];
  __syncthreads();
  float P[16], S[16];
#pragma unroll
  for (int n = 0; n < 16; ++n) { P[n] = 1.f; S[n] = 0.f; }
  for (int tau = 0; tau < 32; ++tau) {
    const size_t bt = btBase + tau;
    const float pre = dtg[(bt << 10) + d] + bd;
    const float dt = (pre > 20.f ? pre : __logf(1.f + __expf(pre))) + 1e-5f;
    const float dx = dt * bf2f(xsb[(bt << 10) + d]);
#pragma unroll
    for (int n = 0; n < 16; ++n) {
      const float Av = __expf(a[n] * dt);
      P[n] *= Av;
      S[n] = fmaf(Av, S[n], bxs[tau][n] * dx);
    }
  }
  const size_t base = (size_t)(((b << 6) + c) * 1024 + d) << 4;
#pragma unroll
  for (int q = 0; q < 4; ++q) {
    f4 pv, sv;
#pragma unroll
    for (int j = 0; j < 4; ++j) { pv[j] = P[q * 4 + j]; sv[j] = S[q * 4 + j]; }
    *(f4*)(Pc + base + q * 4) = pv;
    *(f4*)(Sc + base + q * 4) = sv;
  }
}

__global__ void k_scanB(const float* __restrict__ Pc, const float* __restrict__ Sc,
                        float* __restrict__ SI) {
  const int i = (blockIdx.x << 8) + threadIdx.x;  // 32768
  const int n = i & 15;
  const int dd = (i >> 4) & 1023;
  const int b = i >> 14;
  float s = 0.f;
  for (int c = 0; c < 64; ++c) {
    const size_t idx = ((size_t)(((b << 6) + c) * 1024 + dd) << 4) + n;
    SI[idx] = s;
    s = fmaf(Pc[idx], s, Sc[idx]);
  }
}

__global__ void k_scanC(const float* __restrict__ dtg, const float* __restrict__ b_dt,
                        const u16* __restrict__ xsb, const float* __restrict__ xdbl,
                        const float* __restrict__ A_log, const float* __restrict__ SI,
                        const float* __restrict__ W_C, const float* __restrict__ D_param,
                        u16* __restrict__ yb) {
  __shared__ float bxs[32][32];  // [tau][0:16)=B, [16:32)=C
  const int tid = threadIdx.x;
  const int d = (blockIdx.x << 8) + tid;
  const int c = blockIdx.y;
  const int b = blockIdx.z;
  const int btBase = (b << 11) + (c << 5);
  for (int i = tid; i < 1024; i += 256) {
    bxs[i >> 5][i & 31] = xdbl[(size_t)(btBase + (i >> 5)) * 96 + 64 + (i & 31)];
  }
  float a[16], wc[16];
  {
    const f4* al = (const f4*)(A_log + d * 16);
    const f4* wcp = (const f4*)(W_C + d * 16);
#pragma unroll
    for (int q = 0; q < 4; ++q) {
      f4 v = al[q], u = wcp[q];
#pragma unroll
      for (int j = 0; j < 4; ++j) { a[q * 4 + j] = -__expf(v[j]); wc[q * 4 + j] = u[j]; }
    }
  }
  const float bd = b_dt[d];
  const float Dp = D_param[d];
  float s[16];
  const size_t base = (size_t)(((b << 6) + c) * 1024 + d) << 4;
#pragma unroll
  for (int q = 0; q < 4; ++q) {
    f4 v = *(const f4*)(SI + base + q * 4);
#pragma unroll
    for (int j = 0; j < 4; ++j) s[q * 4 + j] = v[j];
  }
  __syncthreads();
  for (int tau = 0; tau < 32; ++tau) {
    const size_t bt = btBase + tau;
    const float pre = dtg[(bt << 10) + d] + bd;
    const float dt = (pre > 20.f ? pre : __logf(1.f + __expf(pre))) + 1e-5f;
    const float xs = bf2f(xsb[(bt << 10) + d]);
    const float dx = dt * xs;
    float ssum = 0.f, cp = 0.f;
#pragma unroll
    for (int n = 0; n < 16; ++n) {
      const float Av = __expf(a[n] * dt);
      s[n] = fmaf(Av, s[n], bxs[tau][n] * dx);
      ssum += s[n];
      cp = fmaf(bxs[tau][16 + n], wc[n], cp);
    }
    const float y = fmaf(cp, ssum, Dp * xs);
    yb[(bt << 10) + d] = f2bf(y);
  }
}

extern "C" void kernel_launch(void* const* d_in, const int* in_sizes, int n_in,
                              void* d_out, int out_size, void* d_ws, size_t ws_size,
                              hipStream_t stream) {
  const float* x     = (const float*)d_in[0];
  const float* W_in  = (const float*)d_in[1];
  const float* convw = (const float*)d_in[2];
  const float* W_x   = (const float*)d_in[3];
  const float* W_dt  = (const float*)d_in[4];
  const float* b_dt  = (const float*)d_in[5];
  const float* A_log = (const float*)d_in[6];
  const float* D_par = (const float*)d_in[7];
  const float* W_C   = (const float*)d_in[8];
  const float* W_out = (const float*)d_in[9];
  float* out = (float*)d_out;
  (void)in_sizes; (void)n_in; (void)out_size; (void)ws_size;

  char* w = (char*)d_ws;
  auto take = [&](size_t bytes) { char* p = w; w += (bytes + 255) & ~(size_t)255; return p; };
  u16* xb     = (u16*)take(8388608);    // x bf16 [4096][1024]
  u16* w1b    = (u16*)take(4194304);    // W_in bf16 [2048][1024]
  u16* wxb    = (u16*)take(262144);     // W_x bf16 padded [128][1024]
  u16* wob    = (u16*)take(2097152);    // W_out bf16 [1024][1024]
  u16* wdtb   = (u16*)take(131072);     // W_dt bf16 [1024][64]
  u16* xdblb  = (u16*)take(786432);     // x_dbl bf16 [4096][96]
  u16* yb     = (u16*)take(8388608);    // y bf16 [4096][1024]
  u16* xsb    = (u16*)take(8388608);    // xs bf16 [4096][1024]
  float* xz   = (float*)take(33554432); // [4096][2048] fp32
  float* xdblp= (float*)take(6291456);  // split-K parts [4][4096][96]
  float* xdbl = (float*)take(1572864);  // [4096][96] fp32
  float* dtg  = (float*)take(16777216); // dt pre-activation [4096][1024]
  float* Pc   = (float*)take(8388608);  // [b][c=64][d][n]
  float* Sc   = (float*)take(8388608);
  float* SI   = (float*)take(8388608);

  // converts (fused)
  k_cvt_all<<<7360, 256, 0, stream>>>(x, W_in, W_out, W_dt, W_x,
                                      xb, w1b, wob, wdtb, wxb);
  // GEMM1: xz = x @ W_in^T  (4096 x 2048 x 1024)
  dim3 g1(16, 32, 1);
  k_gemm_bt<0><<<g1, 256, 0, stream>>>(xb, 1024, w1b, 1024, xz, 2048, 2048, 1024, 1024,
                                       0, 4, nullptr, 0, 0);
  // conv + silu -> xs bf16
  k_conv2<<<512, 256, 0, stream>>>(xz, convw, xsb);
  // GEMM2: x_dbl = xs @ W_x^T (deterministic split-K=4 into parts)
  dim3 g2(1, 32, 4);
  k_gemm_bt<0><<<g2, 256, 0, stream>>>(xsb, 1024, wxb, 1024, xdblp, 96, 96, 1024, 256,
                                       393216, 0, nullptr, 0, 0);
  k_red4<<<384, 256, 0, stream>>>(xdblp, xdbl, xdblb);
  // dt GEMM: dtg = dt_param @ W_dt^T (K=64)
  dim3 g4(8, 32, 1);
  k_gemm_bt<0><<<g4, 256, 0, stream>>>(xdblb, 96, wdtb, 64, dtg, 1024, 1024, 64, 64,
                                       0, 3, nullptr, 0, 0);
  // chunked scan (L=32, NC=64), softplus/dtx/cproj fused
  dim3 gs(4, 64, 2);
  k_scanA<<<gs, 256, 0, stream>>>(dtg, b_dt, xsb, xdbl, A_log, Pc, Sc);
  k_scanB<<<128, 256, 0, stream>>>(Pc, Sc, SI);
  k_scanC<<<gs, 256, 0, stream>>>(dtg, b_dt, xsb, xdbl, A_log, SI, W_C, D_par, yb);
  // GEMM3: out = (y @ W_out^T) * silu(z)
  dim3 g3(8, 32, 1);
  k_gemm_bt<1><<<g3, 256, 0, stream>>>(yb, 1024, wob, 1024, out, 1024, 1024, 1024, 1024,
                                       0, 3, xz, 2048, 1024);
}